// Round 3
// baseline (347.083 us; speedup 1.0000x reference)
//
#include <hip/hip_runtime.h>
#include <hip/hip_bf16.h>

#define S_LEN 2048
#define HIDV  3072
#define NHQ   24
#define NKVH  8
#define HDIM  128

typedef __bf16 bf16x8 __attribute__((ext_vector_type(8)));
typedef float  f32x4  __attribute__((ext_vector_type(4)));
typedef int    i32x4  __attribute__((ext_vector_type(4)));

__device__ __forceinline__ void gload_lds16(const void* g, void* l) {
    __builtin_amdgcn_global_load_lds((__attribute__((address_space(1))) void*)g,
                                     (__attribute__((address_space(3))) void*)l, 16, 0, 0);
}

// ---------------- cast f32 -> bf16, 4 elems/thread ----------------
__global__ void cast_f32_bf16(const float* __restrict__ in, __hip_bfloat16* __restrict__ out, int n) {
    int i = (blockIdx.x * blockDim.x + threadIdx.x) * 4;
    if (i >= n) return;
    float4 v = *(const float4*)(in + i);
    union { __hip_bfloat16 h[4]; ushort4 u; } pk;
    pk.h[0] = __float2bfloat16(v.x);
    pk.h[1] = __float2bfloat16(v.y);
    pk.h[2] = __float2bfloat16(v.z);
    pk.h[3] = __float2bfloat16(v.w);
    *(ushort4*)(out + i) = pk.u;
}

// ---------------- O-proj GEMM (2-phase 128^2): C[M,N] f32 = A[M,K] * B[N,K]^T ----------------
__global__ void gemm_bt(const __hip_bfloat16* __restrict__ A,
                        const __hip_bfloat16* __restrict__ B,
                        float* __restrict__ C, int M, int N, int K)
{
    __shared__ __hip_bfloat16 As[128 * 32];
    __shared__ __hip_bfloat16 Bs[128 * 32];
    const int tid = threadIdx.x;
    const int w    = tid >> 6;
    const int lane = tid & 63;
    const int lr = lane & 15, lg = lane >> 4;
    const int bm = blockIdx.y, bn = blockIdx.x;
    const int wr = w >> 1, wc = w & 1;
    const int sm = lane >> 2, sk8 = lane & 3;

    f32x4 zf = {0.f, 0.f, 0.f, 0.f};
    f32x4 acc[4][4];
#pragma unroll
    for (int i = 0; i < 4; ++i)
#pragma unroll
        for (int j = 0; j < 4; ++j) acc[i][j] = zf;

    const __hip_bfloat16* Abase = A + (size_t)(bm * 128) * K;
    const __hip_bfloat16* Bbase = B + (size_t)(bn * 128) * K;

    for (int k0 = 0; k0 < K; k0 += 32) {
#pragma unroll
        for (int t = 0; t < 2; ++t) {
            int m = (w + 4 * t) * 16 + sm;
            gload_lds16(Abase + (size_t)m * K + k0 + sk8 * 8, As + m * 32 + sk8 * 8);
            gload_lds16(Bbase + (size_t)m * K + k0 + sk8 * 8, Bs + m * 32 + sk8 * 8);
        }
        __syncthreads();
        bf16x8 af[4], bfr[4];
#pragma unroll
        for (int i = 0; i < 4; ++i) {
            af[i]  = *(const bf16x8*)(As + (wr * 64 + i * 16 + lr) * 32 + lg * 8);
            bfr[i] = *(const bf16x8*)(Bs + (wc * 64 + i * 16 + lr) * 32 + lg * 8);
        }
#pragma unroll
        for (int mi = 0; mi < 4; ++mi)
#pragma unroll
            for (int ni = 0; ni < 4; ++ni)
                acc[mi][ni] = __builtin_amdgcn_mfma_f32_16x16x32_bf16(af[mi], bfr[ni], acc[mi][ni], 0, 0, 0);
        __syncthreads();
    }

#pragma unroll
    for (int mi = 0; mi < 4; ++mi)
#pragma unroll
        for (int ni = 0; ni < 4; ++ni)
#pragma unroll
            for (int j = 0; j < 4; ++j) {
                int row = bm * 128 + wr * 64 + mi * 16 + lg * 4 + j;
                int col = bn * 128 + wc * 64 + ni * 16 + lr;
                C[(size_t)row * N + col] = acc[mi][ni][j];
            }
}

// ================= fused QKV GEMM, 256^2 8-phase template =================
// A[2048][3072] bf16, B[5120][3072] bf16 (rows = output cols).
// cols [0,3072) -> qf f32; [3072,4096) -> kf f32; [4096,5120) -> vbt bf16 transposed.
#define GQ_K  3072
#define GQ_KB 6144   // row bytes
#define GQ_T  48     // K-tiles of 64

#define SBAR()  do { __builtin_amdgcn_sched_barrier(0); __builtin_amdgcn_s_barrier(); __builtin_amdgcn_sched_barrier(0); } while (0)
#define LGKM0() do { asm volatile("s_waitcnt lgkmcnt(0)" ::: "memory"); __builtin_amdgcn_sched_barrier(0); } while (0)
#define VMW(N)  do { asm volatile("s_waitcnt vmcnt(" #N ")" ::: "memory"); __builtin_amdgcn_sched_barrier(0); } while (0)

// stage one 128-row half (16KB) of a [256][64] bf16 tile: per wave 2x gload_lds16,
// linear LDS dest, inverse-swizzled global source (st_16x32: L ^= ((L>>9)&1)<<5).
#define QKV_STAGE(g, regionOff, BI, tcur, h) do {                                   \
    _Pragma("unroll")                                                               \
    for (int j_ = 0; j_ < 2; ++j_) {                                                \
        int L_  = (h) * 16384 + j_ * 8192 + wid * 1024 + lane * 16;                 \
        int Lg_ = L_ ^ (((L_ >> 9) & 1) << 5);                                      \
        gload_lds16((g) + (size_t)(Lg_ >> 7) * GQ_KB + (size_t)(tcur) * 128 + (Lg_ & 127), \
                    smem + (regionOff) + (BI) * 32768 + (h) * 16384 + j_ * 8192 + wid * 1024); \
    } } while (0)

#define QKV_READ_A(AF, BI, MH) do {                                                 \
    _Pragma("unroll")                                                               \
    for (int mr_ = 0; mr_ < 4; ++mr_) {                                             \
        _Pragma("unroll")                                                           \
        for (int k_ = 0; k_ < 2; ++k_) {                                            \
            int row_ = wm * 128 + (MH) * 64 + mr_ * 16 + lr;                        \
            int L_ = row_ * 128 + k_ * 64 + lg * 16;                                \
            AF[mr_][k_] = *(const bf16x8*)(smem + (BI) * 32768 + (L_ ^ (((L_ >> 9) & 1) << 5))); \
        } } } while (0)

#define QKV_READ_B(BF, BI, NH) do {                                                 \
    _Pragma("unroll")                                                               \
    for (int nr_ = 0; nr_ < 2; ++nr_) {                                             \
        _Pragma("unroll")                                                           \
        for (int k_ = 0; k_ < 2; ++k_) {                                            \
            int row_ = wn * 64 + (NH) * 32 + nr_ * 16 + lr;                         \
            int L_ = row_ * 128 + k_ * 64 + lg * 16;                                \
            BF[nr_][k_] = *(const bf16x8*)(smem + 65536 + (BI) * 32768 + (L_ ^ (((L_ >> 9) & 1) << 5))); \
        } } } while (0)

#define QKV_MFMA(AF, BF, MH, NH) do {                                               \
    _Pragma("unroll")                                                               \
    for (int mr_ = 0; mr_ < 4; ++mr_) {                                             \
        _Pragma("unroll")                                                           \
        for (int nr_ = 0; nr_ < 2; ++nr_) {                                         \
            _Pragma("unroll")                                                       \
            for (int k_ = 0; k_ < 2; ++k_)                                          \
                acc[(MH) * 4 + mr_][(NH) * 2 + nr_] = __builtin_amdgcn_mfma_f32_16x16x32_bf16( \
                    AF[mr_][k_], BF[nr_][k_], acc[(MH) * 4 + mr_][(NH) * 2 + nr_], 0, 0, 0); \
        } } } while (0)

// One K-tile = 4 phases. Quadrant order (mh,nh): (0,0),(1,0),(1,1),(0,1).
// A-region of buffer BI is dead after p1 -> stage tile t+2's A halves at p2/p3.
// B-region of buffer BI^1 is dead since previous block -> stage t+1's B at p0/p1.
// Boundary wait: vmcnt(4) (t+1's A halves stay in flight); vmcnt(0) only at last tile.
#define QKV_TILE(BI, tcur) do {                                                     \
    if ((tcur) == GQ_T - 1) { VMW(0); } else { VMW(4); }                            \
    SBAR();                                                                         \
    QKV_READ_A(af0, BI, 0); QKV_READ_B(bf0, BI, 0);                                 \
    if ((tcur) + 1 < GQ_T) QKV_STAGE(Bg, 65536, (BI) ^ 1, (tcur) + 1, 0);           \
    LGKM0();                                                                        \
    __builtin_amdgcn_s_setprio(1); QKV_MFMA(af0, bf0, 0, 0); __builtin_amdgcn_s_setprio(0); \
    SBAR();                                                                         \
    QKV_READ_A(af1, BI, 1);                                                         \
    if ((tcur) + 1 < GQ_T) QKV_STAGE(Bg, 65536, (BI) ^ 1, (tcur) + 1, 1);           \
    LGKM0();                                                                        \
    __builtin_amdgcn_s_setprio(1); QKV_MFMA(af1, bf0, 1, 0); __builtin_amdgcn_s_setprio(0); \
    SBAR();                                                                         \
    QKV_READ_B(bf1, BI, 1);                                                         \
    if ((tcur) + 2 < GQ_T) QKV_STAGE(Ag, 0, BI, (tcur) + 2, 0);                     \
    LGKM0();                                                                        \
    __builtin_amdgcn_s_setprio(1); QKV_MFMA(af1, bf1, 1, 1); __builtin_amdgcn_s_setprio(0); \
    SBAR();                                                                         \
    if ((tcur) + 2 < GQ_T) QKV_STAGE(Ag, 0, BI, (tcur) + 2, 1);                     \
    __builtin_amdgcn_s_setprio(1); QKV_MFMA(af0, bf1, 0, 1); __builtin_amdgcn_s_setprio(0); \
} while (0)

__global__ __launch_bounds__(512, 2) void gemm_qkv_8ph(
    const __hip_bfloat16* __restrict__ A,
    const __hip_bfloat16* __restrict__ B,
    float* __restrict__ qout, float* __restrict__ kout,
    __hip_bfloat16* __restrict__ vout)
{
    extern __shared__ __align__(16) char smem[];  // 128 KiB: A0 A1 B0 B1 (32KB each)
    const int tid = threadIdx.x;
    const int wid = tid >> 6, lane = tid & 63;
    const int wm = wid >> 2, wn = wid & 3;
    const int lr = lane & 15, lg = lane >> 4;

    // XCD-aware swizzle: 160 wgs, 160%8==0 -> each XCD owns one bm (A-panel)
    int bid = blockIdx.x;
    int wg = (bid & 7) * 20 + (bid >> 3);
    int bn = wg % 20, bm = wg / 20;

    const char* Ag = (const char*)A + (size_t)(bm * 256) * GQ_KB;
    const char* Bg = (const char*)B + (size_t)(bn * 256) * GQ_KB;

    f32x4 zf = {0.f, 0.f, 0.f, 0.f};
    f32x4 acc[8][4];
#pragma unroll
    for (int i = 0; i < 8; ++i)
#pragma unroll
        for (int j = 0; j < 4; ++j) acc[i][j] = zf;

    bf16x8 af0[4][2], af1[4][2], bf0[2][2], bf1[2][2];

    // prologue: tile0 (A0,A1,B0,B1) -> buf0; tile1 A halves -> buf1
    QKV_STAGE(Ag, 0, 0, 0, 0); QKV_STAGE(Ag, 0, 0, 0, 1);
    QKV_STAGE(Bg, 65536, 0, 0, 0); QKV_STAGE(Bg, 65536, 0, 0, 1);
    QKV_STAGE(Ag, 0, 1, 1, 0); QKV_STAGE(Ag, 0, 1, 1, 1);

    for (int tt = 0; tt < GQ_T; tt += 2) {
        QKV_TILE(0, tt);
        QKV_TILE(1, tt + 1);
    }

    // epilogue: C-write with segment routing (block-uniform: bn<12 Q, bn<16 K, else V)
#pragma unroll
    for (int mh = 0; mh < 2; ++mh)
#pragma unroll
        for (int mr = 0; mr < 4; ++mr)
#pragma unroll
            for (int nh = 0; nh < 2; ++nh)
#pragma unroll
                for (int nr = 0; nr < 2; ++nr) {
                    int row0 = bm * 256 + wm * 128 + mh * 64 + mr * 16 + lg * 4;
                    int col  = bn * 256 + wn * 64 + nh * 32 + nr * 16 + lr;
                    f32x4 v = acc[mh * 4 + mr][nh * 2 + nr];
                    if (bn < 12) {
#pragma unroll
                        for (int j = 0; j < 4; ++j)
                            qout[(size_t)(row0 + j) * 3072 + col] = v[j];
                    } else if (bn < 16) {
#pragma unroll
                        for (int j = 0; j < 4; ++j)
                            kout[(size_t)(row0 + j) * 1024 + (col - 3072)] = v[j];
                    } else {
                        union { __hip_bfloat16 h[4]; ushort4 u; } pk;
#pragma unroll
                        for (int j = 0; j < 4; ++j) pk.h[j] = __float2bfloat16(v[j]);
                        *(ushort4*)(vout + (size_t)(col - 4096) * 2048 + row0) = pk.u;
                    }
                }
}

// ---------------- RMSNorm + RoPE: one wave per (s, h) row of 128 ----------------
__global__ void norm_rope_kernel(const float* __restrict__ in, __hip_bfloat16* __restrict__ out,
                                 const float* __restrict__ nw, const float* __restrict__ cosp,
                                 const float* __restrict__ sinp, int H, int so_s, int so_h)
{
    int gw = blockIdx.x * 4 + (threadIdx.x >> 6);
    int lane = threadIdx.x & 63;
    int s = gw / H, h = gw - s * H;
    const float* row = in + (size_t)s * (H * HDIM) + h * HDIM;
    float x1 = row[lane], x2 = row[lane + 64];
    float ss = x1 * x1 + x2 * x2;
#pragma unroll
    for (int xm = 1; xm < 64; xm <<= 1) ss += __shfl_xor(ss, xm, 64);
    float rs = rsqrtf(ss * (1.f / 128.f) + 1e-6f);
    float n1 = x1 * rs * (1.f + nw[lane]);
    float n2 = x2 * rs * (1.f + nw[lane + 64]);
    float c1 = cosp[s * HDIM + lane], c2 = cosp[s * HDIM + lane + 64];
    float s1 = sinp[s * HDIM + lane], s2 = sinp[s * HDIM + lane + 64];
    out[(size_t)h * so_h + (size_t)s * so_s + lane]      = __float2bfloat16(n1 * c1 - n2 * s1);
    out[(size_t)h * so_h + (size_t)s * so_s + lane + 64] = __float2bfloat16(n2 * c2 + n1 * s2);
}

// ---------------- Flash attention: causal, GQA 3:1, tanh softcap, fixed-max softmax ----
__global__ __launch_bounds__(128) void attn_kernel(
    const __hip_bfloat16* __restrict__ Q,
    const __hip_bfloat16* __restrict__ Kc,
    const __hip_bfloat16* __restrict__ Vt,
    __hip_bfloat16* __restrict__ O)
{
    __shared__ __hip_bfloat16 Ks[64 * 128];   // [kv][d], xor-swizzled rows of 256B
    __shared__ __hip_bfloat16 Vs[128 * 64];   // [d][kv], xor-swizzled rows of 128B
    __shared__ __hip_bfloat16 Ps[2][16 * 72]; // per-wave P tile

    const int pb = blockIdx.x;  // 0..31
    const int h  = blockIdx.y;
    const int kh = h / (NHQ / NKVH);
    const int tid = threadIdx.x;
    const int w = tid >> 6;
    const int lane = tid & 63;
    const int lr = lane & 15, lg = lane >> 4;

    const char* kg = (const char*)(Kc + (size_t)kh * S_LEN * HDIM);
    const char* vg = (const char*)(Vt + (size_t)kh * HDIM * S_LEN);

    for (int half = 0; half < 2; ++half) {
        const int hb = half ? (63 - pb) : pb;
        const int q0 = hb * 32;
        const int qrow = q0 + w * 16;
        const int jtmax = (q0 + 31) >> 6;

        bf16x8 aq[4];
        {
            const __hip_bfloat16* qp = Q + (size_t)(qrow + lr) * HIDV + h * HDIM + lg * 8;
#pragma unroll
            for (int ks = 0; ks < 4; ++ks) aq[ks] = *(const bf16x8*)(qp + ks * 32);
        }

        f32x4 zf = {0.f, 0.f, 0.f, 0.f};
        f32x4 oacc[8];
#pragma unroll
        for (int i = 0; i < 8; ++i) oacc[i] = zf;
        float lacc[4] = {0.f, 0.f, 0.f, 0.f};

        for (int jt = 0; jt <= jtmax; ++jt) {
            const int j0 = jt * 64;
#pragma unroll
            for (int i = 0; i < 8; ++i) {
                int base = (w * 8 + i) * 1024;
                int L = base + lane * 16;
                int row = L >> 8, c = L & 255;
                gload_lds16(kg + (size_t)(j0 + row) * 256 + (c ^ ((row & 7) << 4)),
                            (char*)Ks + base);
            }
#pragma unroll
            for (int i = 0; i < 8; ++i) {
                int base = (w * 8 + i) * 1024;
                int L = base + lane * 16;
                int row = L >> 7, c = L & 127;
                gload_lds16(vg + (size_t)row * (S_LEN * 2) + j0 * 2 + (c ^ ((row & 7) << 4)),
                            (char*)Vs + base);
            }
            __syncthreads();

            f32x4 sf[4];
#pragma unroll
            for (int nf = 0; nf < 4; ++nf) {
                sf[nf] = zf;
                int row = nf * 16 + lr;
#pragma unroll
                for (int ks = 0; ks < 4; ++ks) {
                    int boff = (row * 256 + ks * 64 + lg * 16) ^ ((row & 7) << 4);
                    bf16x8 bk = *(const bf16x8*)((const char*)Ks + boff);
                    sf[nf] = __builtin_amdgcn_mfma_f32_16x16x32_bf16(aq[ks], bk, sf[nf], 0, 0, 0);
                }
            }

            const bool diag = (jt == jtmax);
            __hip_bfloat16* pw = &Ps[w][0];
#pragma unroll
            for (int nf = 0; nf < 4; ++nf) {
                int jpos = j0 + nf * 16 + lr;
#pragma unroll
                for (int r = 0; r < 4; ++r) {
                    float e2 = __expf(sf[nf][r] * 0.0035355339059327376f); // 2*SCALING/SOFTCAP
                    float rr = __builtin_amdgcn_rcpf(e2 + 1.f);
                    float p  = __expf(fmaf(rr, -100.f, 20.f));
                    if (diag && jpos > (qrow + lg * 4 + r)) p = 0.f;
                    lacc[r] += p;
                    pw[(lg * 4 + r) * 72 + nf * 16 + lr] = __float2bfloat16(p);
                }
            }

#pragma unroll
            for (int ks2 = 0; ks2 < 2; ++ks2) {
                bf16x8 ap = *(const bf16x8*)((const char*)pw + lr * 144 + ks2 * 64 + lg * 16);
#pragma unroll
                for (int df = 0; df < 8; ++df) {
                    int row = df * 16 + lr;
                    int boff = (row * 128 + ks2 * 64 + lg * 16) ^ ((row & 7) << 4);
                    bf16x8 bv = *(const bf16x8*)((const char*)Vs + boff);
                    oacc[df] = __builtin_amdgcn_mfma_f32_16x16x32_bf16(ap, bv, oacc[df], 0, 0, 0);
                }
            }
            __syncthreads();
        }

#pragma unroll
        for (int r = 0; r < 4; ++r) {
            float t = lacc[r];
#pragma unroll
            for (int xm = 1; xm < 16; xm <<= 1) t += __shfl_xor(t, xm, 64);
            float inv = __builtin_amdgcn_rcpf(t);
            size_t rowoff = (size_t)(qrow + lg * 4 + r) * HIDV + h * HDIM;
#pragma unroll
            for (int df = 0; df < 8; ++df)
                O[rowoff + df * 16 + lr] = __float2bfloat16(oacc[df][r] * inv);
        }
    }
}

extern "C" void kernel_launch(void* const* d_in, const int* in_sizes, int n_in,
                              void* d_out, int out_size, void* d_ws, size_t ws_size,
                              hipStream_t stream) {
    const float* hs   = (const float*)d_in[0];
    const float* cosp = (const float*)d_in[1];
    const float* sinp = (const float*)d_in[2];
    // d_in[3] attention_mask — exactly causal, applied analytically in attn_kernel
    const float* wq  = (const float*)d_in[4];
    const float* wk  = (const float*)d_in[5];
    const float* wv  = (const float*)d_in[6];
    const float* wo  = (const float*)d_in[7];
    const float* qnw = (const float*)d_in[8];
    const float* knw = (const float*)d_in[9];
    float* out = (float*)d_out;

    char* ws = (char*)d_ws;
    __hip_bfloat16* hsb = (__hip_bfloat16*)(ws + 0);          // 2048x3072 bf16
    __hip_bfloat16* wf  = (__hip_bfloat16*)(ws + 12582912);   // 5120x3072 bf16 fused QKV weight
    __hip_bfloat16* wob = (__hip_bfloat16*)(ws + 44040192);   // 3072x3072 bf16
    float*          qf  = (float*)(ws + 62914560);            // 2048x3072 f32
    float*          kf  = (float*)(ws + 88080384);            // 2048x1024 f32
    __hip_bfloat16* qb  = (__hip_bfloat16*)(ws + 96468992);   // 2048x3072 bf16
    __hip_bfloat16* kb  = (__hip_bfloat16*)(ws + 109051904);  // [8][2048][128] bf16
    __hip_bfloat16* vbt = (__hip_bfloat16*)(ws + 113246208);  // [8][128][2048] bf16 (V^T)
    __hip_bfloat16* ob  = (__hip_bfloat16*)(ws + 117440512);  // 2048x3072 bf16

    cast_f32_bf16<<<6144, 256, 0, stream>>>(hs, hsb, 6291456);
    cast_f32_bf16<<<9216, 256, 0, stream>>>(wq, wf, 9437184);
    cast_f32_bf16<<<3072, 256, 0, stream>>>(wk, wf + 9437184, 3145728);
    cast_f32_bf16<<<3072, 256, 0, stream>>>(wv, wf + 12582912, 3145728);
    cast_f32_bf16<<<9216, 256, 0, stream>>>(wo, wob, 9437184);

    gemm_qkv_8ph<<<160, 512, 131072, stream>>>(hsb, wf, qf, kf, vbt);

    norm_rope_kernel<<<12288, 256, 0, stream>>>(qf, qb, qnw, cosp, sinp, 24, 3072, 128);
    norm_rope_kernel<<<4096, 256, 0, stream>>>(kf, kb, knw, cosp, sinp, 8, 128, 262144);

    attn_kernel<<<dim3(32, 24), 128, 0, stream>>>(qb, kb, vbt, ob);

    gemm_bt<<<dim3(24, 16), 256, 0, stream>>>(ob, wob, out, 2048, 3072, 3072);
}

// Round 4
// 269.052 us; speedup vs baseline: 1.2900x; 1.2900x over previous
//
#include <hip/hip_runtime.h>
#include <hip/hip_bf16.h>

#define S_LEN 2048
#define HIDV  3072
#define NHQ   24
#define NKVH  8
#define HDIM  128

typedef __bf16 bf16x8 __attribute__((ext_vector_type(8)));
typedef float  f32x4  __attribute__((ext_vector_type(4)));
typedef int    i32x4  __attribute__((ext_vector_type(4)));

__device__ __forceinline__ void gload_lds16(const void* g, void* l) {
    __builtin_amdgcn_global_load_lds((__attribute__((address_space(1))) void*)g,
                                     (__attribute__((address_space(3))) void*)l, 16, 0, 0);
}

// ---------------- cast f32 -> bf16, 4 elems/thread ----------------
__global__ void cast_f32_bf16(const float* __restrict__ in, __hip_bfloat16* __restrict__ out, int n) {
    int i = (blockIdx.x * blockDim.x + threadIdx.x) * 4;
    if (i >= n) return;
    float4 v = *(const float4*)(in + i);
    union { __hip_bfloat16 h[4]; ushort4 u; } pk;
    pk.h[0] = __float2bfloat16(v.x);
    pk.h[1] = __float2bfloat16(v.y);
    pk.h[2] = __float2bfloat16(v.z);
    pk.h[3] = __float2bfloat16(v.w);
    *(ushort4*)(out + i) = pk.u;
}

// ============ 128^2 2-phase GEMM with double-buffered staging (T3-minimum) ============
// C = A[M,K] * B[N,K]^T, bf16 in, f32 acc.
// MODE 0: f32 C0[row*N+col] (O-proj).
// MODE 1: QKV routing over N=5120: bn<24 -> bf16 C0[row*3072+col] (q_pre);
//         bn<32 -> bf16 C1[row*1024+col-3072] (k_pre);
//         else  -> bf16 C2[(col-4096)*2048+row] transposed (V^T), ushort4-packed.
template<int MODE>
__global__ __launch_bounds__(256) void gemm128(const __hip_bfloat16* __restrict__ A,
                                               const __hip_bfloat16* __restrict__ B,
                                               void* __restrict__ C0, void* __restrict__ C1,
                                               void* __restrict__ C2, int M, int N, int K)
{
    __shared__ __hip_bfloat16 As[2][128 * 32];
    __shared__ __hip_bfloat16 Bs[2][128 * 32];
    const int tid = threadIdx.x;
    const int w    = tid >> 6;
    const int lane = tid & 63;
    const int lr = lane & 15, lg = lane >> 4;
    const int bm = blockIdx.y, bn = blockIdx.x;
    const int wr = w >> 1, wc = w & 1;
    const int sm = lane >> 2, sk8 = lane & 3;

    f32x4 zf = {0.f, 0.f, 0.f, 0.f};
    f32x4 acc[4][4];
#pragma unroll
    for (int i = 0; i < 4; ++i)
#pragma unroll
        for (int j = 0; j < 4; ++j) acc[i][j] = zf;

    const __hip_bfloat16* Abase = A + (size_t)(bm * 128) * K;
    const __hip_bfloat16* Bbase = B + (size_t)(bn * 128) * K;
    const int NT = K >> 5;

    // stage K-step t into buffer `buf`: 2 gload_lds16 for A + 2 for B per thread
#define G128_STAGE(buf, t) do {                                                     \
        int k0_ = (t) << 5;                                                         \
        _Pragma("unroll")                                                           \
        for (int tt_ = 0; tt_ < 2; ++tt_) {                                         \
            int m_ = (w + 4 * tt_) * 16 + sm;                                       \
            gload_lds16(Abase + (size_t)m_ * K + k0_ + sk8 * 8, As[buf] + m_ * 32 + sk8 * 8); \
            gload_lds16(Bbase + (size_t)m_ * K + k0_ + sk8 * 8, Bs[buf] + m_ * 32 + sk8 * 8); \
        } } while (0)

    G128_STAGE(0, 0);
    __syncthreads();   // implicit vmcnt(0) before barrier drains staging

    for (int t = 0; t < NT; ++t) {
        const int cur = t & 1;
        if (t + 1 < NT) G128_STAGE(cur ^ 1, t + 1);   // prefetch next while computing
        bf16x8 af[4], bfr[4];
#pragma unroll
        for (int i = 0; i < 4; ++i) {
            af[i]  = *(const bf16x8*)(As[cur] + (wr * 64 + i * 16 + lr) * 32 + lg * 8);
            bfr[i] = *(const bf16x8*)(Bs[cur] + (wc * 64 + i * 16 + lr) * 32 + lg * 8);
        }
#pragma unroll
        for (int mi = 0; mi < 4; ++mi)
#pragma unroll
            for (int ni = 0; ni < 4; ++ni)
                acc[mi][ni] = __builtin_amdgcn_mfma_f32_16x16x32_bf16(af[mi], bfr[ni], acc[mi][ni], 0, 0, 0);
        __syncthreads();   // vmcnt(0): next-tile staging landed; barrier: reads done
    }
#undef G128_STAGE

#pragma unroll
    for (int mi = 0; mi < 4; ++mi)
#pragma unroll
        for (int ni = 0; ni < 4; ++ni) {
            int row0 = bm * 128 + wr * 64 + mi * 16 + lg * 4;
            int col  = bn * 128 + wc * 64 + ni * 16 + lr;
            f32x4 v = acc[mi][ni];
            if (MODE == 0) {
#pragma unroll
                for (int j = 0; j < 4; ++j)
                    ((float*)C0)[(size_t)(row0 + j) * N + col] = v[j];
            } else {
                if (bn < 24) {
#pragma unroll
                    for (int j = 0; j < 4; ++j)
                        ((__hip_bfloat16*)C0)[(size_t)(row0 + j) * 3072 + col] = __float2bfloat16(v[j]);
                } else if (bn < 32) {
#pragma unroll
                    for (int j = 0; j < 4; ++j)
                        ((__hip_bfloat16*)C1)[(size_t)(row0 + j) * 1024 + (col - 3072)] = __float2bfloat16(v[j]);
                } else {
                    union { __hip_bfloat16 h[4]; ushort4 u; } pk;
#pragma unroll
                    for (int j = 0; j < 4; ++j) pk.h[j] = __float2bfloat16(v[j]);
                    *(ushort4*)((__hip_bfloat16*)C2 + (size_t)(col - 4096) * 2048 + row0) = pk.u;
                }
            }
        }
}

// ---------------- RMSNorm + RoPE (bf16 in): one wave per (s, h) row of 128 ----------------
__global__ void norm_rope_kernel(const __hip_bfloat16* __restrict__ in, __hip_bfloat16* __restrict__ out,
                                 const float* __restrict__ nw, const float* __restrict__ cosp,
                                 const float* __restrict__ sinp, int H, int so_s, int so_h)
{
    int gw = blockIdx.x * 4 + (threadIdx.x >> 6);
    int lane = threadIdx.x & 63;
    int s = gw / H, h = gw - s * H;
    const __hip_bfloat16* row = in + (size_t)s * (H * HDIM) + h * HDIM;
    float x1 = __bfloat162float(row[lane]), x2 = __bfloat162float(row[lane + 64]);
    float ss = x1 * x1 + x2 * x2;
#pragma unroll
    for (int xm = 1; xm < 64; xm <<= 1) ss += __shfl_xor(ss, xm, 64);
    float rs = rsqrtf(ss * (1.f / 128.f) + 1e-6f);
    float n1 = x1 * rs * (1.f + nw[lane]);
    float n2 = x2 * rs * (1.f + nw[lane + 64]);
    float c1 = cosp[s * HDIM + lane], c2 = cosp[s * HDIM + lane + 64];
    float s1 = sinp[s * HDIM + lane], s2 = sinp[s * HDIM + lane + 64];
    out[(size_t)h * so_h + (size_t)s * so_s + lane]      = __float2bfloat16(n1 * c1 - n2 * s1);
    out[(size_t)h * so_h + (size_t)s * so_s + lane + 64] = __float2bfloat16(n2 * c2 + n1 * s2);
}

// ---------------- Flash attention: causal, GQA 3:1, tanh softcap, fixed-max softmax ----
// 128 threads / 2 waves. Block pb handles q half-tiles {pb, 63-pb} (32 rows each) -> 33
// kv-tile iterations per block, perfectly balanced.
__global__ __launch_bounds__(128) void attn_kernel(
    const __hip_bfloat16* __restrict__ Q,
    const __hip_bfloat16* __restrict__ Kc,
    const __hip_bfloat16* __restrict__ Vt,
    __hip_bfloat16* __restrict__ O)
{
    __shared__ __hip_bfloat16 Ks[64 * 128];   // [kv][d], xor-swizzled rows of 256B
    __shared__ __hip_bfloat16 Vs[128 * 64];   // [d][kv], xor-swizzled rows of 128B
    __shared__ __hip_bfloat16 Ps[2][16 * 72]; // per-wave P tile

    const int pb = blockIdx.x;  // 0..31
    const int h  = blockIdx.y;
    const int kh = h / (NHQ / NKVH);
    const int tid = threadIdx.x;
    const int w = tid >> 6;
    const int lane = tid & 63;
    const int lr = lane & 15, lg = lane >> 4;

    const char* kg = (const char*)(Kc + (size_t)kh * S_LEN * HDIM);
    const char* vg = (const char*)(Vt + (size_t)kh * HDIM * S_LEN);

    for (int half = 0; half < 2; ++half) {
        const int hb = half ? (63 - pb) : pb;
        const int q0 = hb * 32;
        const int qrow = q0 + w * 16;
        const int jtmax = (q0 + 31) >> 6;

        bf16x8 aq[4];
        {
            const __hip_bfloat16* qp = Q + (size_t)(qrow + lr) * HIDV + h * HDIM + lg * 8;
#pragma unroll
            for (int ks = 0; ks < 4; ++ks) aq[ks] = *(const bf16x8*)(qp + ks * 32);
        }

        f32x4 zf = {0.f, 0.f, 0.f, 0.f};
        f32x4 oacc[8];
#pragma unroll
        for (int i = 0; i < 8; ++i) oacc[i] = zf;
        float lacc[4] = {0.f, 0.f, 0.f, 0.f};

        for (int jt = 0; jt <= jtmax; ++jt) {
            const int j0 = jt * 64;
#pragma unroll
            for (int i = 0; i < 8; ++i) {
                int base = (w * 8 + i) * 1024;
                int L = base + lane * 16;
                int row = L >> 8, c = L & 255;
                gload_lds16(kg + (size_t)(j0 + row) * 256 + (c ^ ((row & 7) << 4)),
                            (char*)Ks + base);
            }
#pragma unroll
            for (int i = 0; i < 8; ++i) {
                int base = (w * 8 + i) * 1024;
                int L = base + lane * 16;
                int row = L >> 7, c = L & 127;
                gload_lds16(vg + (size_t)row * (S_LEN * 2) + j0 * 2 + (c ^ ((row & 7) << 4)),
                            (char*)Vs + base);
            }
            __syncthreads();

            f32x4 sf[4];
#pragma unroll
            for (int nf = 0; nf < 4; ++nf) {
                sf[nf] = zf;
                int row = nf * 16 + lr;
#pragma unroll
                for (int ks = 0; ks < 4; ++ks) {
                    int boff = (row * 256 + ks * 64 + lg * 16) ^ ((row & 7) << 4);
                    bf16x8 bk = *(const bf16x8*)((const char*)Ks + boff);
                    sf[nf] = __builtin_amdgcn_mfma_f32_16x16x32_bf16(aq[ks], bk, sf[nf], 0, 0, 0);
                }
            }

            const bool diag = (jt == jtmax);
            __hip_bfloat16* pw = &Ps[w][0];
#pragma unroll
            for (int nf = 0; nf < 4; ++nf) {
                int jpos = j0 + nf * 16 + lr;
#pragma unroll
                for (int r = 0; r < 4; ++r) {
                    float e2 = __expf(sf[nf][r] * 0.0035355339059327376f); // 2*SCALING/SOFTCAP
                    float rr = __builtin_amdgcn_rcpf(e2 + 1.f);
                    float p  = __expf(fmaf(rr, -100.f, 20.f));
                    if (diag && jpos > (qrow + lg * 4 + r)) p = 0.f;
                    lacc[r] += p;
                    pw[(lg * 4 + r) * 72 + nf * 16 + lr] = __float2bfloat16(p);
                }
            }

#pragma unroll
            for (int ks2 = 0; ks2 < 2; ++ks2) {
                bf16x8 ap = *(const bf16x8*)((const char*)pw + lr * 144 + ks2 * 64 + lg * 16);
#pragma unroll
                for (int df = 0; df < 8; ++df) {
                    int row = df * 16 + lr;
                    int boff = (row * 128 + ks2 * 64 + lg * 16) ^ ((row & 7) << 4);
                    bf16x8 bv = *(const bf16x8*)((const char*)Vs + boff);
                    oacc[df] = __builtin_amdgcn_mfma_f32_16x16x32_bf16(ap, bv, oacc[df], 0, 0, 0);
                }
            }
            __syncthreads();
        }

#pragma unroll
        for (int r = 0; r < 4; ++r) {
            float t = lacc[r];
#pragma unroll
            for (int xm = 1; xm < 16; xm <<= 1) t += __shfl_xor(t, xm, 64);
            float inv = __builtin_amdgcn_rcpf(t);
            size_t rowoff = (size_t)(qrow + lg * 4 + r) * HIDV + h * HDIM;
#pragma unroll
            for (int df = 0; df < 8; ++df)
                O[rowoff + df * 16 + lr] = __float2bfloat16(oacc[df][r] * inv);
        }
    }
}

extern "C" void kernel_launch(void* const* d_in, const int* in_sizes, int n_in,
                              void* d_out, int out_size, void* d_ws, size_t ws_size,
                              hipStream_t stream) {
    const float* hs   = (const float*)d_in[0];
    const float* cosp = (const float*)d_in[1];
    const float* sinp = (const float*)d_in[2];
    // d_in[3] attention_mask — exactly causal, applied analytically in attn_kernel
    const float* wq  = (const float*)d_in[4];
    const float* wk  = (const float*)d_in[5];
    const float* wv  = (const float*)d_in[6];
    const float* wo  = (const float*)d_in[7];
    const float* qnw = (const float*)d_in[8];
    const float* knw = (const float*)d_in[9];
    float* out = (float*)d_out;

    char* ws = (char*)d_ws;
    __hip_bfloat16* hsb  = (__hip_bfloat16*)(ws + 0);          // 2048x3072 bf16
    __hip_bfloat16* wf   = (__hip_bfloat16*)(ws + 12582912);   // 5120x3072 bf16 fused QKV weight
    __hip_bfloat16* wob  = (__hip_bfloat16*)(ws + 44040192);   // 3072x3072 bf16
    __hip_bfloat16* qpre = (__hip_bfloat16*)(ws + 62914560);   // 2048x3072 bf16 (pre-norm Q)
    __hip_bfloat16* kpre = (__hip_bfloat16*)(ws + 75497472);   // 2048x1024 bf16 (pre-norm K)
    __hip_bfloat16* qb   = (__hip_bfloat16*)(ws + 79691776);   // 2048x3072 bf16
    __hip_bfloat16* kb   = (__hip_bfloat16*)(ws + 92274688);   // [8][2048][128] bf16
    __hip_bfloat16* vbt  = (__hip_bfloat16*)(ws + 96468992);   // [8][128][2048] bf16 (V^T)
    __hip_bfloat16* ob   = (__hip_bfloat16*)(ws + 100663296);  // 2048x3072 bf16

    cast_f32_bf16<<<6144, 256, 0, stream>>>(hs, hsb, 6291456);
    cast_f32_bf16<<<9216, 256, 0, stream>>>(wq, wf, 9437184);
    cast_f32_bf16<<<3072, 256, 0, stream>>>(wk, wf + 9437184, 3145728);
    cast_f32_bf16<<<3072, 256, 0, stream>>>(wv, wf + 12582912, 3145728);
    cast_f32_bf16<<<9216, 256, 0, stream>>>(wo, wob, 9437184);

    gemm128<1><<<dim3(40, 16), 256, 0, stream>>>(hsb, wf, qpre, kpre, vbt, 2048, 5120, 3072);

    norm_rope_kernel<<<12288, 256, 0, stream>>>(qpre, qb, qnw, cosp, sinp, 24, 3072, 128);
    norm_rope_kernel<<<4096, 256, 0, stream>>>(kpre, kb, knw, cosp, sinp, 8, 128, 262144);

    attn_kernel<<<dim3(32, 24), 128, 0, stream>>>(qb, kb, vbt, ob);

    gemm128<0><<<dim3(24, 16), 256, 0, stream>>>(ob, wob, out, (void*)0, (void*)0, 2048, 3072, 3072);
}